// Round 1
// baseline (344.759 us; speedup 1.0000x reference)
//
#include <hip/hip_runtime.h>
#include <hip/hip_bf16.h>
#include <stdint.h>

// Problem: B=16, S=2048, I=1024, H=1024  (all fp32 in/out)
// out[b,s,h] = tanh( sum_i x[b,s,i]*W_ih[h,i] + b_ih[h] + sum_k hx[b,k]*W_hh[h,k] + b_hh[h] )
// M = B*S = 32768, N = H = 1024, K = I = 1024.

#define M_TOT 32768
#define N_TOT 1024
#define K_TOT 1024

typedef short short8 __attribute__((ext_vector_type(8)));   // 8 bf16 (4 VGPRs)
typedef float f32x4  __attribute__((ext_vector_type(4)));   // 4 fp32 acc

// ---- workspace layout (bytes) ----
// [0, 67108864)            X_bf   : 33554432 bf16
// [67108864, 69206016)     W_bf   : 1048576 bf16
// [69206016, 69271552)     h_term : 16384 fp32
#define WS_XBF_OFF   0
#define WS_WBF_OFF   67108864
#define WS_HT_OFF    69206016

__device__ __forceinline__ unsigned short f32_to_bf16_rne(float f) {
    union { float f; unsigned int u; } v; v.f = f;
    unsigned int u = v.u;
    unsigned int r = u + 0x7fffu + ((u >> 16) & 1u);
    return (unsigned short)(r >> 16);
}

__device__ __forceinline__ float fast_tanh(float z) {
    // tanh(z) = 1 - 2/(exp(2z)+1); __expf -> v_exp_f32. Saturates correctly at +-inf.
    float e = __expf(2.0f * z);
    return 1.0f - 2.0f / (e + 1.0f);
}

// ---------------- kernel 1: fp32 -> bf16 convert (X and W_ih) ----------------
__global__ void convert_kernel(const float* __restrict__ x,
                               const float* __restrict__ wih,
                               unsigned short* __restrict__ xbf,
                               unsigned short* __restrict__ wbf) {
    const int NXV = 33554432 / 8;  // vec8 groups in X
    const int NWV = 1048576 / 8;   // vec8 groups in W_ih
    int stride = gridDim.x * blockDim.x;
    for (int v = blockIdx.x * blockDim.x + threadIdx.x; v < NXV + NWV; v += stride) {
        const float* src; unsigned short* dst; long long base;
        if (v < NXV) { src = x;   dst = xbf; base = (long long)v * 8; }
        else         { src = wih; dst = wbf; base = (long long)(v - NXV) * 8; }
        float4 a = *(const float4*)(src + base);
        float4 b = *(const float4*)(src + base + 4);
        union { unsigned short s[8]; uint4 u; } o;
        o.s[0] = f32_to_bf16_rne(a.x); o.s[1] = f32_to_bf16_rne(a.y);
        o.s[2] = f32_to_bf16_rne(a.z); o.s[3] = f32_to_bf16_rne(a.w);
        o.s[4] = f32_to_bf16_rne(b.x); o.s[5] = f32_to_bf16_rne(b.y);
        o.s[6] = f32_to_bf16_rne(b.z); o.s[7] = f32_to_bf16_rne(b.w);
        *(uint4*)(dst + base) = o.u;
    }
}

// ---------------- kernel 2: h_term[b,h] = hx[b,:].W_hh[h,:] + b_ih[h] + b_hh[h] ----------------
__global__ void hterm_kernel(const float* __restrict__ hx,
                             const float* __restrict__ whh,
                             const float* __restrict__ bih,
                             const float* __restrict__ bhh,
                             float* __restrict__ ht) {
    int lane = threadIdx.x & 63;
    int w    = threadIdx.x >> 6;
    int wg   = blockIdx.x * 4 + w;        // 0..16383
    int b = wg >> 10, h = wg & 1023;
    const float* hr = hx  + (long long)b * 1024;
    const float* wr = whh + (long long)h * 1024;
    float s = 0.f;
#pragma unroll
    for (int p = 0; p < 4; ++p) {
        int idx = p * 256 + lane * 4;
        float4 a = *(const float4*)(hr + idx);
        float4 c = *(const float4*)(wr + idx);
        s += a.x * c.x + a.y * c.y + a.z * c.z + a.w * c.w;
    }
#pragma unroll
    for (int d = 32; d > 0; d >>= 1) s += __shfl_down(s, d, 64);
    if (lane == 0) ht[wg] = s + bih[h] + bhh[h];
}

// ---------------- kernel 3: bf16 MFMA GEMM + tanh epilogue ----------------
// 128x128 tile, BK=32, 256 threads = 4 waves in 2x2, each wave 64x64 (4x4 MFMA 16x16x32).
// global_load_lds width=16 staging with XOR chunk swizzle: chunk slot = (q + (row>>1)) & 3
// so ds_read_b128 fragment reads are only 2-way bank aliased (free).
#define GLDS16(gp, lp) \
    __builtin_amdgcn_global_load_lds((const __attribute__((address_space(1))) void*)(gp), \
                                     (__attribute__((address_space(3))) void*)(lp), 16, 0, 0)

__global__ __launch_bounds__(256) void gemm_tanh_kernel(
    const unsigned short* __restrict__ A,   // [32768,1024] bf16 (X)
    const unsigned short* __restrict__ Bm,  // [1024,1024]  bf16 (W_ih, row n is K-contiguous)
    const float* __restrict__ ht,           // [16,1024]
    float* __restrict__ out)                // [32768,1024] fp32
{
    __shared__ __align__(16) char lds[16384];   // A tile: [0,8192), B tile: [8192,16384)

    const int tid = threadIdx.x;
    const int w = tid >> 6, l = tid & 63;
    const int bid = blockIdx.x;
    const int tile_n = bid & 7;        // 8 n-tiles; consecutive bids share the A row-tile (L2/L3 reuse)
    const int tile_m = bid >> 3;       // 256 m-tiles
    const int m0 = tile_m << 7, n0 = tile_n << 7;

    // ---- staging addresses (2 A-instr + 2 B-instr per thread per K-iter) ----
    // wave w, instr j covers tile rows [(w*2+j)*16, +16); lane l -> row +(l>>2), 16B slot (l&3).
    // Slot s holds global chunk qg = (s - (row>>1)) & 3  (inverse of the read swizzle).
    const int r0 = (w * 2 + 0) * 16 + (l >> 2);
    const int r1 = (w * 2 + 1) * 16 + (l >> 2);
    const int slot = l & 3;
    const int qg0 = (slot - (r0 >> 1)) & 3;
    const int qg1 = (slot - (r1 >> 1)) & 3;
    const unsigned short* gA0 = A  + (long long)(m0 + r0) * K_TOT + qg0 * 8;
    const unsigned short* gA1 = A  + (long long)(m0 + r1) * K_TOT + qg1 * 8;
    const unsigned short* gB0 = Bm + (long long)(n0 + r0) * K_TOT + qg0 * 8;
    const unsigned short* gB1 = Bm + (long long)(n0 + r1) * K_TOT + qg1 * 8;
    char* ldsA0 = lds + (w * 2 + 0) * 1024;
    char* ldsA1 = lds + (w * 2 + 1) * 1024;
    char* ldsB0 = lds + 8192 + (w * 2 + 0) * 1024;
    char* ldsB1 = lds + 8192 + (w * 2 + 1) * 1024;

    // ---- fragment read offsets ----
    const int wm = w & 1, wn = w >> 1;       // 2x2 wave grid
    const int lm = l & 15, q = l >> 4;       // MFMA operand: row = lm, k-chunk = q
    int offA[4], offB[4];
#pragma unroll
    for (int t = 0; t < 4; ++t) {
        int rr = wm * 64 + t * 16 + lm;
        offA[t] = rr * 64 + (((q + (rr >> 1)) & 3) << 4);
        int nn = wn * 64 + t * 16 + lm;
        offB[t] = 8192 + nn * 64 + (((q + (nn >> 1)) & 3) << 4);
    }

    f32x4 acc[4][4];
#pragma unroll
    for (int i = 0; i < 4; ++i)
#pragma unroll
        for (int j = 0; j < 4; ++j)
            acc[i][j] = (f32x4){0.f, 0.f, 0.f, 0.f};

    for (int k0 = 0; k0 < K_TOT; k0 += 32) {
        GLDS16(gA0 + k0, ldsA0);
        GLDS16(gA1 + k0, ldsA1);
        GLDS16(gB0 + k0, ldsB0);
        GLDS16(gB1 + k0, ldsB1);
        __syncthreads();   // compiler drains vmcnt before s_barrier

        short8 af[4], bf[4];
#pragma unroll
        for (int t = 0; t < 4; ++t) {
            af[t] = *(const short8*)(lds + offA[t]);
            bf[t] = *(const short8*)(lds + offB[t]);
        }
#pragma unroll
        for (int mt = 0; mt < 4; ++mt)
#pragma unroll
            for (int nt = 0; nt < 4; ++nt)
                acc[mt][nt] = __builtin_amdgcn_mfma_f32_16x16x32_bf16(
                    af[mt], bf[nt], acc[mt][nt], 0, 0, 0);
        __syncthreads();
    }

    // ---- epilogue: out = tanh(acc + h_term[b, n]) ----
    // C/D layout: col = lane&15 (n), row = (lane>>4)*4 + reg (m).  [guide §3, m89-verified]
    const int b = tile_m >> 4;   // S=2048 -> 16 m-tiles per batch row; block is within one b
    float htv[4];
#pragma unroll
    for (int nt = 0; nt < 4; ++nt)
        htv[nt] = ht[b * 1024 + n0 + wn * 64 + nt * 16 + lm];

#pragma unroll
    for (int mt = 0; mt < 4; ++mt) {
#pragma unroll
        for (int nt = 0; nt < 4; ++nt) {
            int n = n0 + wn * 64 + nt * 16 + lm;
#pragma unroll
            for (int r = 0; r < 4; ++r) {
                int m = m0 + wm * 64 + mt * 16 + q * 4 + r;
                float z = acc[mt][nt][r] + htv[nt];
                out[(long long)m * N_TOT + n] = fast_tanh(z);
            }
        }
    }
}

extern "C" void kernel_launch(void* const* d_in, const int* in_sizes, int n_in,
                              void* d_out, int out_size, void* d_ws, size_t ws_size,
                              hipStream_t stream) {
    const float* x    = (const float*)d_in[0];   // [16,2048,1024]
    const float* hx   = (const float*)d_in[1];   // [16,1024]
    const float* wih  = (const float*)d_in[2];   // [1024,1024]
    const float* whh  = (const float*)d_in[3];   // [1024,1024]
    const float* bih  = (const float*)d_in[4];   // [1024]
    const float* bhh  = (const float*)d_in[5];   // [1024]
    float* out = (float*)d_out;

    unsigned short* xbf = (unsigned short*)((char*)d_ws + WS_XBF_OFF);
    unsigned short* wbf = (unsigned short*)((char*)d_ws + WS_WBF_OFF);
    float*          htp = (float*)((char*)d_ws + WS_HT_OFF);

    // h_term: 16384 outputs, 1 wave each, 4 waves/block
    hterm_kernel<<<4096, 256, 0, stream>>>(hx, whh, bih, bhh, htp);
    // fp32 -> bf16 for X and W_ih
    convert_kernel<<<2048, 256, 0, stream>>>(x, wih, xbf, wbf);
    // GEMM + tanh: 256 m-tiles x 8 n-tiles
    gemm_tanh_kernel<<<2048, 256, 0, stream>>>(xbf, wbf, htp, out);
}